// Round 5
// baseline (627.427 us; speedup 1.0000x reference)
//
#include <hip/hip_runtime.h>
#include <hip/hip_bf16.h>

// Problem constants: B=4, S=1024, F=1024, E=8, K=2, H=4*F=4096
constexpr int Ff = 1024;
constexpr int Ee = 8;
constexpr int Hh = 4096;
constexpr int T  = 4096;        // B*S tokens
constexpr int MB = 72;          // max padded m-blocks: ceil((8192+8*127)/128)

typedef short     bf16x8 __attribute__((ext_vector_type(8)));
typedef float     f32x4  __attribute__((ext_vector_type(4)));
typedef unsigned short u16x8 __attribute__((ext_vector_type(8)));

__device__ __forceinline__ float gelu_tanh(float v) {
  const float c = 0.7978845608028654f;  // sqrt(2/pi)
  float t = tanhf(c * (v + 0.044715f * v * v * v));
  return 0.5f * v * (1.0f + t);
}

__device__ __forceinline__ unsigned short bf16bits(float f) {
  __hip_bfloat16 h = __float2bfloat16(f);
  return *reinterpret_cast<unsigned short*>(&h);
}

__device__ __forceinline__ void gl_lds16(const void* g, void* l) {
  __builtin_amdgcn_global_load_lds(
      (const __attribute__((address_space(1))) unsigned int*)g,
      (__attribute__((address_space(3))) unsigned int*)l, 16, 0, 0);
}

// ---------------- Gating (fp32, exact routing) ----------------
__global__ __launch_bounds__(256) void gating_kernel(
    const float* __restrict__ x, const float* __restrict__ Wg,
    const float* __restrict__ bg, int* __restrict__ cnt,
    int* __restrict__ list, float* __restrict__ wlist) {
  const int wave = threadIdx.x >> 6;
  const int lane = threadIdx.x & 63;
  const int t = blockIdx.x * 4 + wave;
  float acc[Ee] = {0.f,0.f,0.f,0.f,0.f,0.f,0.f,0.f};
  const float* xrow = x + (size_t)t * Ff;
  for (int f0 = 0; f0 < Ff; f0 += 64) {
    float xv = xrow[f0 + lane];
    const float* wrow = Wg + (size_t)(f0 + lane) * Ee;
    float4 w0 = *reinterpret_cast<const float4*>(wrow);
    float4 w1 = *reinterpret_cast<const float4*>(wrow + 4);
    acc[0] += xv * w0.x; acc[1] += xv * w0.y;
    acc[2] += xv * w0.z; acc[3] += xv * w0.w;
    acc[4] += xv * w1.x; acc[5] += xv * w1.y;
    acc[6] += xv * w1.z; acc[7] += xv * w1.w;
  }
#pragma unroll
  for (int e = 0; e < Ee; ++e) {
#pragma unroll
    for (int off = 32; off; off >>= 1) acc[e] += __shfl_xor(acc[e], off);
  }
  if (lane == 0) {
    float l[Ee], m = -1e30f;
#pragma unroll
    for (int e = 0; e < Ee; ++e) { l[e] = acc[e] + bg[e]; m = fmaxf(m, l[e]); }
    float p[Ee], Z = 0.f;
#pragma unroll
    for (int e = 0; e < Ee; ++e) { p[e] = expf(l[e] - m); Z += p[e]; }
#pragma unroll
    for (int e = 0; e < Ee; ++e) p[e] /= Z;
    int i1 = 0; float p1 = p[0];
#pragma unroll
    for (int e = 1; e < Ee; ++e) if (p[e] > p1) { p1 = p[e]; i1 = e; }
    int i2 = -1; float p2 = -1e30f;
#pragma unroll
    for (int e = 0; e < Ee; ++e) if (e != i1 && p[e] > p2) { p2 = p[e]; i2 = e; }
    float denom = p1 + p2 + 1e-8f;
    int pos = atomicAdd(&cnt[i1], 1);
    list[i1 * T + pos] = t; wlist[i1 * T + pos] = p1 / denom;
    pos = atomicAdd(&cnt[i2], 1);
    list[i2 * T + pos] = t; wlist[i2 * T + pos] = p2 / denom;
  }
}

// 128-aligned expert row offsets (padded flattened row space)
__global__ void prefix_kernel(const int* __restrict__ cnt, int* __restrict__ offs) {
  if (threadIdx.x == 0) {
    int s = 0;
    for (int e = 0; e < Ee; ++e) { offs[e] = s; s += (cnt[e] + 127) & ~127; }
    offs[Ee] = s;
  }
}

// ---------------- x fp32 -> bf16 ----------------
__global__ __launch_bounds__(256) void cvt_x_kernel(
    const float* __restrict__ x, unsigned short* __restrict__ xb) {
  const size_t i = ((size_t)blockIdx.x * 256 + threadIdx.x) * 8;
  float4 a = *reinterpret_cast<const float4*>(x + i);
  float4 b = *reinterpret_cast<const float4*>(x + i + 4);
  u16x8 o;
  o[0] = bf16bits(a.x); o[1] = bf16bits(a.y); o[2] = bf16bits(a.z); o[3] = bf16bits(a.w);
  o[4] = bf16bits(b.x); o[5] = bf16bits(b.y); o[6] = bf16bits(b.z); o[7] = bf16bits(b.w);
  *reinterpret_cast<u16x8*>(xb + i) = o;
}

// -------- transpose + convert: dst[e][col][row] (bf16) = src[e][row][col] (fp32) --------
__global__ __launch_bounds__(256) void transpose_cvt_kernel(
    const float* __restrict__ src, unsigned short* __restrict__ dst,
    int s_rstride, int d_rstride, size_t s_estride, size_t d_estride) {
  const int e  = blockIdx.z;
  const int r0 = blockIdx.y * 64;
  const int c0 = blockIdx.x * 64;
  __shared__ __align__(16) unsigned short Ts[64][72];
  const int t = threadIdx.x;
  const float* sb = src + (size_t)e * s_estride + (size_t)r0 * s_rstride + c0;
  {
    const int rr = t >> 4;
    const int cc = (t & 15) * 4;
#pragma unroll
    for (int i = 0; i < 4; ++i) {
      float4 v = *reinterpret_cast<const float4*>(sb + (size_t)(rr + i * 16) * s_rstride + cc);
      Ts[cc + 0][rr + i * 16] = bf16bits(v.x);
      Ts[cc + 1][rr + i * 16] = bf16bits(v.y);
      Ts[cc + 2][rr + i * 16] = bf16bits(v.z);
      Ts[cc + 3][rr + i * 16] = bf16bits(v.w);
    }
  }
  __syncthreads();
  {
    const int n  = t >> 2;
    const int ks = (t & 3) * 16;
    unsigned short* db = dst + (size_t)e * d_estride + (size_t)(c0 + n) * d_rstride + r0 + ks;
    *reinterpret_cast<ulonglong2*>(db)     = *reinterpret_cast<const ulonglong2*>(&Ts[n][ks]);
    *reinterpret_cast<ulonglong2*>(db + 8) = *reinterpret_cast<const ulonglong2*>(&Ts[n][ks + 8]);
  }
}

// ---------------- GEMM1: h = gelu(xb[tokens] @ W1T^T + b1), depth-3 pipeline ----------------
__global__ __launch_bounds__(256) void gemm1_mfma(
    const unsigned short* __restrict__ xb, const unsigned short* __restrict__ W1T,
    const float* __restrict__ b1, const int* __restrict__ cnt,
    const int* __restrict__ offs, const int* __restrict__ list,
    unsigned short* __restrict__ h, int Hc, int c, int nxg) {
  const int nwg = nxg * MB;
  int bid = blockIdx.x + nxg * blockIdx.y;
  bid = (bid & 7) * (nwg >> 3) + (bid >> 3);
  const int bx = bid % nxg, by = bid / nxg;

  const int m0g = by * 128;
  int e = 0;
#pragma unroll
  for (int i = 1; i < Ee; ++i) e += (m0g >= offs[i]) ? 1 : 0;
  const int ce = cnt[e];
  const int mloc = m0g - offs[e];
  if (mloc >= ce) return;
  const int n0 = bx * 128;

  __shared__ __align__(16) unsigned short As[3][4][128][8];
  __shared__ __align__(16) unsigned short Bs[3][4][128][8];
  const int tid = threadIdx.x;
  const int w = tid >> 6, lane = tid & 63;
  const int g = lane >> 4, r16 = lane & 15;
  const int wr = w >> 1, wc = w & 1;
  const int tok0 = (mloc + lane < ce)      ? list[e * T + mloc + lane]      : 0;
  const int tok1 = (mloc + 64 + lane < ce) ? list[e * T + mloc + 64 + lane] : 0;
  const unsigned short* a0p = xb + (size_t)tok0 * Ff + w * 8;
  const unsigned short* a1p = xb + (size_t)tok1 * Ff + w * 8;
  const unsigned short* b0p = W1T + (size_t)e * Hc * Ff + (size_t)(n0 + lane) * Ff + w * 8;
  const unsigned short* b1p = b0p + (size_t)64 * Ff;

  f32x4 acc[4][4] = {};
  constexpr int nt = Ff / 32;
  auto STAGE = [&](int buf, int kt) {
    const int k0 = kt * 32;
    unsigned short* aB = &As[buf][0][0][0] + w * 1024;
    unsigned short* bB = &Bs[buf][0][0][0] + w * 1024;
    gl_lds16(a0p + k0, aB);
    gl_lds16(a1p + k0, aB + 512);
    gl_lds16(b0p + k0, bB);
    gl_lds16(b1p + k0, bB + 512);
  };
  STAGE(0, 0);
  STAGE(1, 1);
  STAGE(2, 2);
  int cur = 0;
#pragma unroll 1
  for (int t = 0; t < nt; ++t) {
    const int rem = nt - t;   // stages still in flight (incl. current), capped at 3
    if (rem >= 3)      asm volatile("s_waitcnt vmcnt(8)" ::: "memory");
    else if (rem == 2) asm volatile("s_waitcnt vmcnt(4)" ::: "memory");
    else               asm volatile("s_waitcnt vmcnt(0)" ::: "memory");
    __builtin_amdgcn_s_barrier();
    bf16x8 af[4], bfr[4];
#pragma unroll
    for (int i = 0; i < 4; ++i) {
      af[i]  = *reinterpret_cast<const bf16x8*>(&As[cur][g][wr * 64 + i * 16 + r16][0]);
      bfr[i] = *reinterpret_cast<const bf16x8*>(&Bs[cur][g][wc * 64 + i * 16 + r16][0]);
    }
    asm volatile("s_waitcnt lgkmcnt(0)" ::: "memory");
    __builtin_amdgcn_s_barrier();
    if (t + 3 < nt) STAGE(cur, t + 3);   // (t+3)%3 == t%3 == cur
    __builtin_amdgcn_s_setprio(1);
#pragma unroll
    for (int mi = 0; mi < 4; ++mi)
#pragma unroll
      for (int ni = 0; ni < 4; ++ni)
        acc[mi][ni] = __builtin_amdgcn_mfma_f32_16x16x32_bf16(
            af[mi], bfr[ni], acc[mi][ni], 0, 0, 0);
    __builtin_amdgcn_s_setprio(0);
    asm volatile("" ::: "memory");
    cur = (cur == 2) ? 0 : cur + 1;
  }
  const int colbase = n0 + wc * 64;
#pragma unroll
  for (int ni = 0; ni < 4; ++ni) {
    const int col = colbase + ni * 16 + r16;
    const float bias = b1[(size_t)e * Hh + (size_t)c * Hc + col];
#pragma unroll
    for (int mi = 0; mi < 4; ++mi)
#pragma unroll
      for (int r = 0; r < 4; ++r) {
        const int m = wr * 64 + mi * 16 + g * 4 + r;
        if (mloc + m < ce)
          h[(size_t)(m0g + m) * Hc + col] = bf16bits(gelu_tanh(acc[mi][ni][r] + bias));
      }
  }
}

// -------- GEMM2: out[token] += w * (h @ W2T^T (+b2)), depth-3 pipeline, K-split --------
__global__ __launch_bounds__(256) void gemm2_mfma(
    const unsigned short* __restrict__ h, const unsigned short* __restrict__ W2T,
    const float* __restrict__ b2, const int* __restrict__ cnt,
    const int* __restrict__ offs, const int* __restrict__ list,
    const float* __restrict__ wlist, float* __restrict__ out,
    int Hc, int kLen, int biasC) {
  const int nxg = Ff / 128, nzg = Hc / kLen;
  const int nwg = nxg * MB * nzg;
  int bid = blockIdx.x + nxg * (blockIdx.y + MB * blockIdx.z);
  bid = (bid & 7) * (nwg >> 3) + (bid >> 3);
  const int bx = bid % nxg, by = (bid / nxg) % MB, bz = bid / (nxg * MB);
  const int kOff = bz * kLen;

  const int m0g = by * 128;
  int e = 0;
#pragma unroll
  for (int i = 1; i < Ee; ++i) e += (m0g >= offs[i]) ? 1 : 0;
  const int ce = cnt[e];
  const int mloc = m0g - offs[e];
  if (mloc >= ce) return;
  const int n0 = bx * 128;

  __shared__ __align__(16) unsigned short As[3][4][128][8];
  __shared__ __align__(16) unsigned short Bs[3][4][128][8];
  const int tid = threadIdx.x;
  const int w = tid >> 6, lane = tid & 63;
  const int g = lane >> 4, r16 = lane & 15;
  const int wr = w >> 1, wc = w & 1;
  const unsigned short* a0p = h + (size_t)(m0g + lane) * Hc + kOff + w * 8;
  const unsigned short* a1p = a0p + (size_t)64 * Hc;
  const unsigned short* b0p = W2T + (size_t)e * Ff * Hc + (size_t)(n0 + lane) * Hc + kOff + w * 8;
  const unsigned short* b1p = b0p + (size_t)64 * Hc;

  f32x4 acc[4][4] = {};
  const int nt = kLen / 32;
  auto STAGE = [&](int buf, int kt) {
    const int k0 = kt * 32;
    unsigned short* aB = &As[buf][0][0][0] + w * 1024;
    unsigned short* bB = &Bs[buf][0][0][0] + w * 1024;
    gl_lds16(a0p + k0, aB);
    gl_lds16(a1p + k0, aB + 512);
    gl_lds16(b0p + k0, bB);
    gl_lds16(b1p + k0, bB + 512);
  };
  STAGE(0, 0);
  if (nt > 1) STAGE(1, 1);
  if (nt > 2) STAGE(2, 2);
  int cur = 0;
#pragma unroll 1
  for (int t = 0; t < nt; ++t) {
    const int rem = nt - t;
    if (rem >= 3)      asm volatile("s_waitcnt vmcnt(8)" ::: "memory");
    else if (rem == 2) asm volatile("s_waitcnt vmcnt(4)" ::: "memory");
    else               asm volatile("s_waitcnt vmcnt(0)" ::: "memory");
    __builtin_amdgcn_s_barrier();
    bf16x8 af[4], bfr[4];
#pragma unroll
    for (int i = 0; i < 4; ++i) {
      af[i]  = *reinterpret_cast<const bf16x8*>(&As[cur][g][wr * 64 + i * 16 + r16][0]);
      bfr[i] = *reinterpret_cast<const bf16x8*>(&Bs[cur][g][wc * 64 + i * 16 + r16][0]);
    }
    asm volatile("s_waitcnt lgkmcnt(0)" ::: "memory");
    __builtin_amdgcn_s_barrier();
    if (t + 3 < nt) STAGE(cur, t + 3);
    __builtin_amdgcn_s_setprio(1);
#pragma unroll
    for (int mi = 0; mi < 4; ++mi)
#pragma unroll
      for (int ni = 0; ni < 4; ++ni)
        acc[mi][ni] = __builtin_amdgcn_mfma_f32_16x16x32_bf16(
            af[mi], bfr[ni], acc[mi][ni], 0, 0, 0);
    __builtin_amdgcn_s_setprio(0);
    asm volatile("" ::: "memory");
    cur = (cur == 2) ? 0 : cur + 1;
  }
  const bool addBias = (biasC != 0) && (bz == 0);
#pragma unroll
  for (int mi = 0; mi < 4; ++mi)
#pragma unroll
    for (int r = 0; r < 4; ++r) {
      const int m = wr * 64 + mi * 16 + g * 4 + r;
      if (mloc + m >= ce) continue;
      const int token = list[e * T + mloc + m];
      const float wgt = wlist[e * T + mloc + m];
      float* op = out + (size_t)token * Ff;
#pragma unroll
      for (int ni = 0; ni < 4; ++ni) {
        const int col = n0 + wc * 64 + ni * 16 + r16;
        float v = acc[mi][ni][r];
        if (addBias) v += b2[(size_t)e * Ff + col];
        atomicAdd(&op[col], wgt * v);
      }
    }
}

extern "C" void kernel_launch(void* const* d_in, const int* in_sizes, int n_in,
                              void* d_out, int out_size, void* d_ws, size_t ws_size,
                              hipStream_t stream) {
  const float* x  = (const float*)d_in[0];
  const float* Wg = (const float*)d_in[1];
  const float* bg = (const float*)d_in[2];
  const float* W1 = (const float*)d_in[3];
  const float* b1 = (const float*)d_in[4];
  const float* W2 = (const float*)d_in[5];
  const float* b2 = (const float*)d_in[6];
  float* out = (float*)d_out;

  // Adaptive H-chunk. fixed = lists + xb; per-Hc-unit = W1T + W2T + h(9216 rows)
  const size_t fixed = 1024 + 2 * (size_t)T * Ee * 4 + (size_t)T * Ff * 2;
  int Hc = 4096;
  while (Hc > 128 && fixed + (size_t)Hc * 51200 > ws_size) Hc >>= 1;
  const int nchunk = Hh / Hc;
  const int ksplit = 2;
  const int kLen = Hc / ksplit;

  char* p = (char*)d_ws;
  int*   cnt   = (int*)p;            p += 512;
  int*   offs  = (int*)p;            p += 512;
  int*   list  = (int*)p;            p += (size_t)T * Ee * 4;
  float* wlist = (float*)p;          p += (size_t)T * Ee * 4;
  unsigned short* xb  = (unsigned short*)p;  p += (size_t)T * Ff * 2;
  unsigned short* W1T = (unsigned short*)p;  p += (size_t)Ee * Hc * Ff * 2;
  unsigned short* W2T = (unsigned short*)p;  p += (size_t)Ee * Ff * Hc * 2;
  unsigned short* h   = (unsigned short*)p;  // 9216 * Hc * 2

  hipMemsetAsync(d_out, 0, (size_t)out_size * sizeof(float), stream);
  hipMemsetAsync(cnt, 0, 64, stream);

  gating_kernel<<<T / 4, 256, 0, stream>>>(x, Wg, bg, cnt, list, wlist);
  prefix_kernel<<<1, 64, 0, stream>>>(cnt, offs);
  cvt_x_kernel<<<(T * Ff) / 2048, 256, 0, stream>>>(x, xb);

  for (int c = 0; c < nchunk; ++c) {
    transpose_cvt_kernel<<<dim3(Hc / 64, Ff / 64, Ee), 256, 0, stream>>>(
        W1 + (size_t)c * Hc, W1T, Hh, Ff, (size_t)Ff * Hh, (size_t)Hc * Ff);
    transpose_cvt_kernel<<<dim3(Ff / 64, Hc / 64, Ee), 256, 0, stream>>>(
        W2 + (size_t)c * Hc * Ff, W2T, Ff, Hc, (size_t)Hh * Ff, (size_t)Ff * Hc);
    gemm1_mfma<<<dim3(Hc / 128, MB), 256, 0, stream>>>(
        xb, W1T, b1, cnt, offs, list, h, Hc, c, Hc / 128);
    gemm2_mfma<<<dim3(Ff / 128, MB, ksplit), 256, 0, stream>>>(
        h, W2T, b2, cnt, offs, list, wlist, out, Hc, kLen,
        c == nchunk - 1 ? 1 : 0);
  }
}